// Round 4
// baseline (1847.754 us; speedup 1.0000x reference)
//
#include <hip/hip_runtime.h>
#include <math.h>

typedef unsigned short u16;
typedef unsigned int u32;
typedef __attribute__((ext_vector_type(8))) short bf16x8;
typedef __attribute__((ext_vector_type(16))) float f32x16;
typedef __attribute__((ext_vector_type(4))) float f4v;
typedef __attribute__((ext_vector_type(4))) u32 u32x4;

#define MFMA(a, b, c) __builtin_amdgcn_mfma_f32_32x32x16_bf16(a, b, c, 0, 0, 0)

// one barrier per pipeline step: wait own prefetch loads, then block barrier
#define PIPE_SYNC() do {                                   \
    asm volatile("s_waitcnt vmcnt(0)" ::: "memory");       \
    __builtin_amdgcn_s_barrier();                          \
    __builtin_amdgcn_sched_barrier(0);                     \
} while (0)

// ---------------- helpers ----------------
__device__ __forceinline__ float bf2f(u16 h) { return __uint_as_float(((u32)h) << 16); }

__device__ __forceinline__ void split2(float v, u16& h, u16& l) {
    u32 u = __float_as_uint(v);
    u32 hr = (u + 0x7FFFu + ((u >> 16) & 1u)) & 0xFFFF0000u;
    h = (u16)(hr >> 16);
    float lf = v - __uint_as_float(hr);
    u32 ul = __float_as_uint(lf);
    l = (u16)((ul + 0x7FFFu + ((ul >> 16) & 1u)) >> 16);
}

__device__ __forceinline__ u32 cvtpk(float lo, float hi) {
    u32 r;
    asm("v_cvt_pk_bf16_f32 %0, %1, %2" : "=v"(r) : "v"(lo), "v"(hi));
    return r;
}

__device__ __forceinline__ void swap32(u32& a, u32& b, int hi) {
    u32 ta = (u32)__shfl_xor((int)a, 32);
    u32 tb = (u32)__shfl_xor((int)b, 32);
    u32 na = hi ? tb : a;
    u32 nb = hi ? b : ta;
    a = na; b = nb;
}

// P regs v[base..base+7] (f32, S^T layout) -> A-fragment hi + exact lo residual
__device__ __forceinline__ void repack(const f32x16& v, int base, int hi, bf16x8& fh, bf16x8& fl) {
    float p0 = v[base + 0], p1 = v[base + 1], p2 = v[base + 2], p3 = v[base + 3];
    float p4 = v[base + 4], p5 = v[base + 5], p6 = v[base + 6], p7 = v[base + 7];
    u32 X0 = cvtpk(p0, p1), X1 = cvtpk(p2, p3), X4 = cvtpk(p4, p5), X5 = cvtpk(p6, p7);
    float r0 = p0 - __uint_as_float(X0 << 16);
    float r1 = p1 - __uint_as_float(X0 & 0xFFFF0000u);
    float r2 = p2 - __uint_as_float(X1 << 16);
    float r3 = p3 - __uint_as_float(X1 & 0xFFFF0000u);
    float r4 = p4 - __uint_as_float(X4 << 16);
    float r5 = p5 - __uint_as_float(X4 & 0xFFFF0000u);
    float r6 = p6 - __uint_as_float(X5 << 16);
    float r7 = p7 - __uint_as_float(X5 & 0xFFFF0000u);
    u32 L0 = cvtpk(r0, r1), L1 = cvtpk(r2, r3), L4 = cvtpk(r4, r5), L5 = cvtpk(r6, r7);
    swap32(X0, X4, hi); swap32(X1, X5, hi);
    swap32(L0, L4, hi); swap32(L1, L5, hi);
    u32x4 th = {X0, X1, X4, X5};
    u32x4 tl = {L0, L1, L4, L5};
    fh = __builtin_bit_cast(bf16x8, th);
    fl = __builtin_bit_cast(bf16x8, tl);
}

// ---------------- PE table ----------------
__global__ __launch_bounds__(256) void pe_kernel(float* __restrict__ pe) {
    int idx = blockIdx.x * 256 + threadIdx.x;      // < 1024*768
    int n = idx / 768, d = idx - n * 768;
    float v = 0.0f;
    if (d < 384) {
        int pos = (d < 192) ? (n >> 5) : (n & 31);
        int dd  = (d < 192) ? d : d - 192;
        int j2  = dd & ~1;
        float dv  = expf((float)j2 * (-9.210340371976184f / 192.0f));
        float ang = (float)pos * dv;
        v = (dd & 1) ? cosf(ang) : sinf(ang);
    }
    pe[idx] = v;
}

// ---------------- patch gather ----------------
__global__ __launch_bounds__(256) void gather_kernel(const float* __restrict__ x,
                                                     u16* __restrict__ xph,
                                                     u16* __restrict__ xpl) {
    int idx = blockIdx.x * 256 + threadIdx.x;      // < 2048*768
    int m = idx / 768, col = idx - m * 768;
    int b = m >> 10, n = m & 1023;
    int ci = col >> 8, rem = col & 255;
    int pr = rem >> 4, pc = rem & 15;
    int hh = ((n >> 5) << 4) + pr;
    int ww = ((n & 31) << 4) + pc;
    float v = x[(((size_t)(b * 3 + ci) * 512) + hh) * 512 + ww];
    split2(v, xph[idx], xpl[idx]);
}

// ---------------- fp32 -> hi/lo split ----------------
__global__ __launch_bounds__(256) void fsplit(const float* __restrict__ in,
                                              u16* __restrict__ h, u16* __restrict__ l, int n4) {
    int i = blockIdx.x * 256 + threadIdx.x;
    if (i >= n4) return;
    float4 v = ((const float4*)in)[i];
    int o = i * 4;
    split2(v.x, h[o], l[o]);
    split2(v.y, h[o + 1], l[o + 1]);
    split2(v.z, h[o + 2], l[o + 2]);
    split2(v.w, h[o + 3], l[o + 3]);
}

// ---------------- per-layer weight split ----------------
__global__ __launch_bounds__(256) void wsplit_layer(const float* __restrict__ qkvw,
                                                    const float* __restrict__ projw,
                                                    const float* __restrict__ w1,
                                                    const float* __restrict__ w2,
                                                    u16* __restrict__ wh, u16* __restrict__ wl) {
    int i4 = blockIdx.x * 256 + threadIdx.x;       // < 1179648
    if (i4 >= 1179648) return;
    size_t idx = (size_t)i4 * 4;
    const float* src; size_t off;
    if (idx < 1769472)      { src = qkvw;  off = idx; }
    else if (idx < 2359296) { src = projw; off = idx - 1769472; }
    else if (idx < 3538944) { src = w1;    off = idx - 2359296; }
    else                    { src = w2;    off = idx - 3538944; }
    float4 v = *(const float4*)(src + off);
    split2(v.x, wh[idx], wl[idx]);
    split2(v.y, wh[idx + 1], wl[idx + 1]);
    split2(v.z, wh[idx + 2], wl[idx + 2]);
    split2(v.w, wh[idx + 3], wl[idx + 3]);
}

// ---------------- LayerNorm -> hi/lo ----------------
__global__ __launch_bounds__(256) void ln_kernel(const float* __restrict__ x,
                                                 const float* __restrict__ g,
                                                 const float* __restrict__ b,
                                                 u16* __restrict__ yh, u16* __restrict__ yl) {
    int row = blockIdx.x, tid = threadIdx.x;
    const float* xr = x + (size_t)row * 768;
    float v0 = xr[tid], v1 = xr[tid + 256], v2 = xr[tid + 512];
    __shared__ float red[256];
    red[tid] = v0 + v1 + v2;
    __syncthreads();
    for (int off = 128; off > 0; off >>= 1) {
        if (tid < off) red[tid] += red[tid + off];
        __syncthreads();
    }
    float mean = red[0] * (1.0f / 768.0f);
    __syncthreads();
    float d0 = v0 - mean, d1 = v1 - mean, d2 = v2 - mean;
    red[tid] = d0 * d0 + d1 * d1 + d2 * d2;
    __syncthreads();
    for (int off = 128; off > 0; off >>= 1) {
        if (tid < off) red[tid] += red[tid + off];
        __syncthreads();
    }
    float rstd = rsqrtf(red[0] * (1.0f / 768.0f) + 1e-5f);
    size_t o = (size_t)row * 768;
    split2(d0 * rstd * g[tid]       + b[tid],       yh[o + tid],       yl[o + tid]);
    split2(d1 * rstd * g[tid + 256] + b[tid + 256], yh[o + tid + 256], yl[o + tid + 256]);
    split2(d2 * rstd * g[tid + 512] + b[tid + 512], yh[o + tid + 512], yl[o + tid + 512]);
}

// ---------------- split-bf16 MFMA GEMM (single-barrier prefetch pipeline) ----------------
// MODE 1: C=acc+bias+pe  MODE 2: C=res+(auxh+auxl)+acc+bias  MODE 3: gelu->split
// MODE 4: C=res+acc+bias MODE 5: relu->split  MODE 6: C=acc+bias  MODE 7: split
template <int MODE>
__global__ __launch_bounds__(256, 2) void gemm_sp(const u16* __restrict__ Ah, const u16* __restrict__ Al,
                                                  const u16* __restrict__ Bh, const u16* __restrict__ Bl,
                                                  const float* __restrict__ bias,
                                                  const float* __restrict__ res,
                                                  const float* __restrict__ auxf,
                                                  const u16* __restrict__ auxh, const u16* __restrict__ auxl,
                                                  float* __restrict__ C, u16* __restrict__ Ch, u16* __restrict__ Cl,
                                                  int M, int N, int K) {
    __shared__ u16 smem[2][4][4096];   // 64 KB
    int tid = threadIdx.x;
    int wid = tid >> 6, lane = tid & 63;
    int wm = wid >> 1, wn = wid & 1;
    int m0 = blockIdx.y * 128, n0 = blockIdx.x * 128;

    int srow_in = lane >> 2;
    int schunk = lane & 3;

    int arow = wm * 64 + (lane & 31);
    int aoff0 = arow * 32 + ((((lane >> 5) ^ (arow & 3))) << 3);
    int brow = wn * 64 + (lane & 31);
    int boff0 = brow * 32 + ((((lane >> 5) ^ (brow & 3))) << 3);

    f32x16 acc00 = {}, acc01 = {}, acc10 = {}, acc11 = {};

    const u16* srcs[4] = {Ah, Al, Bh, Bl};
    int rbase[4] = {m0, m0, n0, n0};

    auto stage = [&](int buf, int kt) {
#pragma unroll
        for (int t = 0; t < 4; ++t) {
            const u16* G = srcs[t];
#pragma unroll
            for (int j = 0; j < 2; ++j) {
                int row = wid * 32 + j * 16 + srow_in;
                int gchunk = schunk ^ (row & 3);
                const u16* g = G + (size_t)(rbase[t] + row) * K + kt + gchunk * 8;
                u16* ldst = &smem[buf][t][(wid * 32 + j * 16) * 32];
                __builtin_amdgcn_global_load_lds((const __attribute__((address_space(1))) u32*)g,
                                                 (__attribute__((address_space(3))) u32*)ldst, 16, 0, 0);
            }
        }
    };

    auto compute = [&](int buf) {
        const u16* Sah = smem[buf][0];
        const u16* Sal = smem[buf][1];
        const u16* Sbh = smem[buf][2];
        const u16* Sbl = smem[buf][3];
#pragma unroll
        for (int h = 0; h < 2; ++h) {
            int x = h << 4;
            bf16x8 ah0 = *(const bf16x8*)(Sah + (aoff0 ^ x));
            bf16x8 ah1 = *(const bf16x8*)(Sah + ((aoff0 + 1024) ^ x));
            bf16x8 al0 = *(const bf16x8*)(Sal + (aoff0 ^ x));
            bf16x8 al1 = *(const bf16x8*)(Sal + ((aoff0 + 1024) ^ x));
            bf16x8 bh0 = *(const bf16x8*)(Sbh + (boff0 ^ x));
            bf16x8 bh1 = *(const bf16x8*)(Sbh + ((boff0 + 1024) ^ x));
            bf16x8 bl0 = *(const bf16x8*)(Sbl + (boff0 ^ x));
            bf16x8 bl1 = *(const bf16x8*)(Sbl + ((boff0 + 1024) ^ x));
            acc00 = MFMA(ah0, bh0, acc00);
            acc00 = MFMA(ah0, bl0, acc00);
            acc00 = MFMA(al0, bh0, acc00);
            acc01 = MFMA(ah0, bh1, acc01);
            acc01 = MFMA(ah0, bl1, acc01);
            acc01 = MFMA(al0, bh1, acc01);
            acc10 = MFMA(ah1, bh0, acc10);
            acc10 = MFMA(ah1, bl0, acc10);
            acc10 = MFMA(al1, bh0, acc10);
            acc11 = MFMA(ah1, bh1, acc11);
            acc11 = MFMA(ah1, bl1, acc11);
            acc11 = MFMA(al1, bh1, acc11);
        }
    };

    int nk = K >> 5;
    stage(0, 0);
    for (int t = 0; t < nk; ++t) {
        PIPE_SYNC();                             // wait prefetch, 1 barrier/step
        if (t + 1 < nk) stage((t + 1) & 1, (t + 1) << 5);
        compute(t & 1);
    }

    auto epi = [&](f32x16 a, int fm, int fn) {
        int col = n0 + wn * 64 + fn * 32 + (lane & 31);
        int rb = m0 + wm * 64 + fm * 32 + ((lane >> 5) << 2);
#pragma unroll
        for (int r = 0; r < 16; ++r) {
            int row = rb + (r & 3) + ((r >> 2) << 3);
            float v = a[r];
            size_t o = (size_t)row * N + col;
            if (MODE == 1) C[o] = v + bias[col] + auxf[(size_t)(row & 1023) * N + col];
            else if (MODE == 2) C[o] = res[o] + (bf2f(auxh[o]) + bf2f(auxl[o])) + v + bias[col];
            else if (MODE == 3) {
                v += bias[col];
                v = 0.5f * v * (1.0f + erff(v * 0.70710678118654752f));
                split2(v, Ch[o], Cl[o]);
            }
            else if (MODE == 4) C[o] = res[o] + v + bias[col];
            else if (MODE == 5) {
                v += bias[col];
                v = fmaxf(v, 0.0f);
                split2(v, Ch[o], Cl[o]);
            }
            else if (MODE == 6) C[o] = v + bias[col];
            else if (MODE == 7) split2(v, Ch[o], Cl[o]);
        }
    };
    epi(acc00, 0, 0); epi(acc01, 0, 1); epi(acc10, 1, 0); epi(acc11, 1, 1);
}

// ---------------- V transpose: qkv V-part -> Vt [b][h][hd][1024] ----------------
__global__ __launch_bounds__(256) void vtrans(const u16* __restrict__ qh, const u16* __restrict__ ql,
                                              u16* __restrict__ vth, u16* __restrict__ vtl) {
    __shared__ u16 tl[2][64][72];
    int tid = threadIdx.x;
    int kt = blockIdx.x, bh = blockIdx.y;
    int b = bh / 12, h = bh % 12;
#pragma unroll
    for (int j = 0; j < 2; ++j) {
        int idx = tid + j * 256;
        int r = idx >> 3, c = idx & 7;
        size_t so = (size_t)(b * 1024 + kt * 64 + r) * 2304 + 1536 + h * 64 + c * 8;
        *(bf16x8*)&tl[0][r][c * 8] = *(const bf16x8*)(qh + so);
        *(bf16x8*)&tl[1][r][c * 8] = *(const bf16x8*)(ql + so);
    }
    __syncthreads();
#pragma unroll
    for (int j = 0; j < 2; ++j) {
        int idx = tid + j * 256;
        int hd = idx >> 3, c = idx & 7;
        u16 t0[8], t1[8];
#pragma unroll
        for (int i = 0; i < 8; ++i) { t0[i] = tl[0][c * 8 + i][hd]; t1[i] = tl[1][c * 8 + i][hd]; }
        size_t d = ((size_t)(b * 12 + h) * 64 + hd) * 1024 + kt * 64 + c * 8;
        *(bf16x8*)(vth + d) = *(bf16x8*)t0;
        *(bf16x8*)(vtl + d) = *(bf16x8*)t1;
    }
}

// ---------------- MFMA flash attention (4-slot double-buffered, 1 barrier/step) ----------------
// grid (16 q-tiles, 24 bh), 4 waves: wave(s,p) = (q-half, K-parity)
// K-tiles of 32 rows; 32 tiles; parity p handles tiles 2*ss+p, ss=0..15.
// LDS: smem[p][buf][comp][32*64 u16], comp: 0=Kh 1=Kl 2=Vth 3=Vtl. 64 KB total.
__global__ __launch_bounds__(256, 2) void attn_mfma(const u16* __restrict__ qh, const u16* __restrict__ ql,
                                                    const u16* __restrict__ vth, const u16* __restrict__ vtl,
                                                    const float* __restrict__ bias,
                                                    u16* __restrict__ oh, u16* __restrict__ ol) {
    __shared__ u16 smem[2][2][4][2048];
    int tid = threadIdx.x;
    int wid = tid >> 6, lane = tid & 63;
    int s = wid & 1, p = wid >> 1;
    int lq = lane & 31;
    int hi = lane >> 5;
    int bq0 = blockIdx.x * 64;
    int bh = blockIdx.y;
    int b = bh / 12, h = bh % 12;
    int gq = bq0 + s * 32 + lq;

    // Q fragments in registers
    bf16x8 qfh[4], qfl[4];
    {
        size_t qo = (size_t)(b * 1024 + gq) * 2304 + h * 64 + hi * 8;
#pragma unroll
        for (int ks = 0; ks < 4; ++ks) {
            qfh[ks] = *(const bf16x8*)(qh + qo + ks * 16);
            qfl[ks] = *(const bf16x8*)(ql + qo + ks * 16);
        }
    }

    f32x16 oa = {}, ob = {};
    float m_i = -1e30f, l_i = 0.0f;

    // stage K-tile (32 rows) at k-base kb into smem[p][buf]
    auto stage = [&](int buf, int kb) {
        if (s == 0) {
            // K rows: 32 x 64 hd (128B rows), chunk swizzle c ^ (r&7)
#pragma unroll
            for (int c = 0; c < 2; ++c) {
                const u16* G = c ? ql : qh;
#pragma unroll
                for (int i = 0; i < 4; ++i) {
                    int r = 8 * i + (lane >> 3);
                    int cl = (lane & 7) ^ (r & 7);
                    const u16* g = G + (size_t)(b * 1024 + kb + r) * 2304 + 768 + h * 64 + cl * 8;
                    __builtin_amdgcn_global_load_lds((const __attribute__((address_space(1))) u32*)g,
                                                     (__attribute__((address_space(3))) u32*)&smem[p][buf][c][i * 512],
                                                     16, 0, 0);
                }
            }
        } else {
            // Vt rows: 64 hd x 32 k (64B rows), chunk swizzle c ^ ((r>>1)&3)
#pragma unroll
            for (int c = 0; c < 2; ++c) {
                const u16* G = c ? vtl : vth;
#pragma unroll
                for (int i = 0; i < 4; ++i) {
                    int r = 16 * i + (lane >> 2);
                    int cl = (lane & 3) ^ ((r >> 1) & 3);
                    const u16* g = G + ((size_t)(b * 12 + h) * 64 + r) * 1024 + kb + cl * 8;
                    __builtin_amdgcn_global_load_lds((const __attribute__((address_space(1))) u32*)g,
                                                     (__attribute__((address_space(3))) u32*)&smem[p][buf][2 + c][i * 512],
                                                     16, 0, 0);
                }
            }
        }
    };

    auto compute = [&](int buf, int kb) {
        const u16* Kh = &smem[p][buf][0][0];
        const u16* Kl = &smem[p][buf][1][0];
        const u16* Vh = &smem[p][buf][2][0];
        const u16* Vl = &smem[p][buf][3][0];
        // bias prefetch (independent of MFMAs -> overlaps)
        const float* brow = bias + (size_t)gq * 1024 + kb + (hi << 2);
        f4v bb0 = *(const f4v*)(brow);
        f4v bb1 = *(const f4v*)(brow + 8);
        f4v bb2 = *(const f4v*)(brow + 16);
        f4v bb3 = *(const f4v*)(brow + 24);
        // QK^T (S^T: 32 k-rows x 32 q)
        f32x16 sa = {};
#pragma unroll
        for (int ks = 0; ks < 4; ++ks) {
            int off = lq * 64 + (((2 * ks + hi) ^ (lq & 7)) << 3);
            bf16x8 kha = *(const bf16x8*)(Kh + off);
            bf16x8 kla = *(const bf16x8*)(Kl + off);
            sa = MFMA(kha, qfh[ks], sa);
            sa = MFMA(kha, qfl[ks], sa);
            sa = MFMA(kla, qfh[ks], sa);
        }
        // V fragments prefetch (ds_read latency hides under softmax VALU)
        bf16x8 vf[2][4];
#pragma unroll
        for (int kslot = 0; kslot < 2; ++kslot) {
            int offa = lq * 32 + (((2 * kslot + hi) ^ ((lq >> 1) & 3)) << 3);
            vf[kslot][0] = *(const bf16x8*)(Vh + offa);
            vf[kslot][1] = *(const bf16x8*)(Vh + offa + 1024);
            vf[kslot][2] = *(const bf16x8*)(Vl + offa);
            vf[kslot][3] = *(const bf16x8*)(Vl + offa + 1024);
        }
        // scale + bias
#pragma unroll
        for (int j = 0; j < 4; ++j) {
            sa[j]      = sa[j]      * 0.125f + bb0[j];
            sa[4 + j]  = sa[4 + j]  * 0.125f + bb1[j];
            sa[8 + j]  = sa[8 + j]  * 0.125f + bb2[j];
            sa[12 + j] = sa[12 + j] * 0.125f + bb3[j];
        }
        // online softmax (lane <-> q)
        float mt = sa[0];
#pragma unroll
        for (int r = 1; r < 16; ++r) mt = fmaxf(mt, sa[r]);
        mt = fmaxf(mt, __shfl_xor(mt, 32));
        float mnew = fmaxf(m_i, mt);
        int up = __any(mnew > m_i);
        float scl = __expf(m_i - mnew);
        m_i = mnew;
        float ls = 0.0f;
#pragma unroll
        for (int r = 0; r < 16; ++r) { sa[r] = __expf(sa[r] - mnew); ls += sa[r]; }
        ls += __shfl_xor(ls, 32);
        l_i = l_i * scl + ls;
        if (up) {
#pragma unroll
            for (int r = 0; r < 16; ++r) {
                int qr = (r & 3) + 8 * (r >> 2) + 4 * hi;
                float fr = __shfl(scl, qr);
                oa[r] *= fr; ob[r] *= fr;
            }
        }
        // P repack + PV
#pragma unroll
        for (int kslot = 0; kslot < 2; ++kslot) {
            bf16x8 ph, pl;
            repack(sa, kslot * 8, hi, ph, pl);
            oa = MFMA(ph, vf[kslot][0], oa);
            oa = MFMA(ph, vf[kslot][2], oa);
            oa = MFMA(pl, vf[kslot][0], oa);
            ob = MFMA(ph, vf[kslot][1], ob);
            ob = MFMA(ph, vf[kslot][3], ob);
            ob = MFMA(pl, vf[kslot][1], ob);
        }
    };

    stage(0, p * 32);
    for (int ss = 0; ss < 16; ++ss) {
        PIPE_SYNC();
        if (ss + 1 < 16) stage((ss + 1) & 1, (2 * (ss + 1) + p) * 32);
        compute(ss & 1, (2 * ss + p) * 32);
    }
    __syncthreads();

    // ---- merge K-parity halves ----
    float* mlb = (float*)((char*)smem + 32768);   // [s][p][2][32] floats
    mlb[((s * 2 + p) * 2 + 0) * 32 + lq] = m_i;
    mlb[((s * 2 + p) * 2 + 1) * 32 + lq] = l_i;
    __syncthreads();
    float mo = mlb[((s * 2 + (p ^ 1)) * 2 + 0) * 32 + lq];
    float lo_ = mlb[((s * 2 + (p ^ 1)) * 2 + 1) * 32 + lq];
    float M = fmaxf(m_i, mo);
    float ea = __expf(m_i - M), eb = __expf(mo - M);
    float L = ea * l_i + eb * lo_;
    float f = ea / L;
    float frv[16];
#pragma unroll
    for (int r = 0; r < 16; ++r) frv[r] = __shfl(f, (r & 3) + 8 * (r >> 2) + 4 * hi);
    float* ox = (float*)((char*)smem + s * 8192);  // 32q x 64hd f32 = 8 KB per s
    if (p == 1) {
#pragma unroll
        for (int r = 0; r < 16; ++r) {
            int qr = (r & 3) + 8 * (r >> 2) + 4 * hi;
            ox[qr * 64 + lq] = oa[r] * frv[r];
            ox[qr * 64 + 32 + lq] = ob[r] * frv[r];
        }
    }
    __syncthreads();
    if (p == 0) {
#pragma unroll
        for (int r = 0; r < 16; ++r) {
            int qr = (r & 3) + 8 * (r >> 2) + 4 * hi;
            float va = oa[r] * frv[r] + ox[qr * 64 + lq];
            float vb = ob[r] * frv[r] + ox[qr * 64 + 32 + lq];
            size_t d = (size_t)(b * 1024 + bq0 + s * 32 + qr) * 768 + h * 64;
            split2(va, oh[d + lq], ol[d + lq]);
            split2(vb, oh[d + 32 + lq], ol[d + 32 + lq]);
        }
    }
}

// ---------------- fold + attention gate ----------------
__global__ __launch_bounds__(256) void fold_gate(const float* __restrict__ hbuf,
                                                 const float* __restrict__ xin,
                                                 const float* __restrict__ wg,
                                                 const float* __restrict__ bngw,
                                                 const float* __restrict__ bngb,
                                                 const float* __restrict__ wx,
                                                 const float* __restrict__ bnxw,
                                                 const float* __restrict__ bnxb,
                                                 const float* __restrict__ psiw,
                                                 const float* __restrict__ psib,
                                                 float* __restrict__ out) {
    int idx = blockIdx.x * 256 + threadIdx.x;      // < 2*512*512
    int b = idx >> 18;
    int rem = idx & 262143;
    int hh = rem >> 9, ww = rem & 511;
    int n = ((hh >> 4) << 5) + (ww >> 4);
    int pr = hh & 15, pc = ww & 15;
    const float* hrow = hbuf + (size_t)(b * 1024 + n) * 768 + pr * 16 + pc;
    float g0 = hrow[0], g1 = hrow[256], g2 = hrow[512];
    size_t xoff = ((size_t)(b * 3) * 512 + hh) * 512 + ww;
    float x0 = xin[xoff], x1 = xin[xoff + 262144], x2 = xin[xoff + 524288];
    float inv = rsqrtf(1.0f + 1e-5f);
    float gg = (g0 * wg[0] + g1 * wg[1] + g2 * wg[2]) * inv * bngw[0] + bngb[0];
    float xx = (x0 * wx[0] + x1 * wx[1] + x2 * wx[2]) * inv * bnxw[0] + bnxb[0];
    float z = gg + xx;
    z = z > 0.0f ? z : 0.0f;
    float psi = 1.0f / (1.0f + expf(-(z * psiw[0] + psib[0])));
    out[xoff]          = g0 * x0 * psi;
    out[xoff + 262144] = g1 * x1 * psi;
    out[xoff + 524288] = g2 * x2 * psi;
}

// ---------------- launch ----------------
extern "C" void kernel_launch(void* const* d_in, const int* in_sizes, int n_in,
                              void* d_out, int out_size, void* d_ws, size_t ws_size,
                              hipStream_t stream) {
    (void)in_sizes; (void)n_in; (void)out_size; (void)ws_size;
    const float* x       = (const float*)d_in[0];
    const float* conv_w  = (const float*)d_in[1];
    const float* conv_b  = (const float*)d_in[2];
    const float* ln1_g   = (const float*)d_in[3];
    const float* ln1_b   = (const float*)d_in[4];
    const float* qkv_w   = (const float*)d_in[5];
    const float* proj_w  = (const float*)d_in[6];
    const float* proj_b  = (const float*)d_in[7];
    const float* attn_bs = (const float*)d_in[8];
    const float* ln2_g   = (const float*)d_in[9];
    const float* ln2_b   = (const float*)d_in[10];
    const float* mlp_w1  = (const float*)d_in[11];
    const float* mlp_b1  = (const float*)d_in[12];
    const float* mlp_w2  = (const float*)d_in[13];
    const float* mlp_b2  = (const float*)d_in[14];
    const float* op_w1   = (const float*)d_in[15];
    const float* op_b1   = (const float*)d_in[16];
    const float* op_w2   = (const float*)d_in[17];
    const float* op_b2   = (const float*)d_in[18];
    const float* ag_wg   = (const float*)d_in[19];
    const float* ag_bngw = (const float*)d_in[20];
    const float* ag_bngb = (const float*)d_in[21];
    const float* ag_wx   = (const float*)d_in[22];
    const float* ag_bnxw = (const float*)d_in[23];
    const float* ag_bnxb = (const float*)d_in[24];
    const float* ag_psiw = (const float*)d_in[25];
    const float* ag_psib = (const float*)d_in[26];
    float* out = (float*)d_out;

    // workspace layout (bytes), total 69,206,016
    char* w8 = (char*)d_ws;
    float* t   = (float*)(w8);                        // 6,291,456
    u16* yh    = (u16*)(w8 + 6291456);
    u16* yl    = (u16*)(w8 + 9437184);
    u16* ath   = (u16*)(w8 + 12582912);
    u16* atl   = (u16*)(w8 + 15728640);
    u16* mh    = (u16*)(w8 + 18874368);               // 6,291,456
    u16* ml    = (u16*)(w8 + 25165824);               // 6,291,456
    u16* qh    = (u16*)(w8 + 31457280);               // 9,437,184
    u16* ql    = (u16*)(w8 + 40894464);               // 9,437,184
    u16* wh    = (u16*)(w8 + 50331648);               // 9,437,184
    u16* wl    = (u16*)(w8 + 59768832);               // ends 69,206,016
    float* pe  = (float*)qh;            // alias (pre-layer only)
    u16* xph = mh; u16* xpl = ml;       // alias (consumed by embed gemm)
    u16* vth = mh; u16* vtl = ml;       // alias (attn phase, dead before mlp1)
    float* oph2 = (float*)qh;           // alias (after layers)
    u16* o1h = ath; u16* o1l = atl;     // alias (after layers)

    const size_t W_QKV = 0, W_PROJ = 1769472, W_MLP1 = 2359296, W_MLP2 = 3538944;

    pe_kernel<<<3072, 256, 0, stream>>>(pe);
    gather_kernel<<<6144, 256, 0, stream>>>(x, xph, xpl);
    fsplit<<<576, 256, 0, stream>>>(conv_w, wh, wl, 147456);
    gemm_sp<1><<<dim3(6, 16), 256, 0, stream>>>(xph, xpl, wh, wl, conv_b, nullptr, pe,
                                                nullptr, nullptr, t, nullptr, nullptr, 2048, 768, 768);

    for (int l = 0; l < 8; ++l) {
        wsplit_layer<<<4608, 256, 0, stream>>>(qkv_w + (size_t)l * 1769472, proj_w + (size_t)l * 589824,
                                               mlp_w1 + (size_t)l * 1179648, mlp_w2 + (size_t)l * 1179648,
                                               wh, wl);
        ln_kernel<<<2048, 256, 0, stream>>>(t, ln1_g + l * 768, ln1_b + l * 768, yh, yl);
        gemm_sp<7><<<dim3(18, 16), 256, 0, stream>>>(yh, yl, wh + W_QKV, wl + W_QKV, nullptr, nullptr,
                                                     nullptr, nullptr, nullptr, nullptr, qh, ql,
                                                     2048, 2304, 768);
        vtrans<<<dim3(16, 24), 256, 0, stream>>>(qh, ql, vth, vtl);
        attn_mfma<<<dim3(16, 24), 256, 0, stream>>>(qh, ql, vth, vtl,
                                                    attn_bs + (size_t)l * 1048576, ath, atl);
        gemm_sp<2><<<dim3(6, 16), 256, 0, stream>>>(ath, atl, wh + W_PROJ, wl + W_PROJ, proj_b + l * 768,
                                                    t, nullptr, yh, yl, t, nullptr, nullptr, 2048, 768, 768);
        ln_kernel<<<2048, 256, 0, stream>>>(t, ln2_g + l * 768, ln2_b + l * 768, yh, yl);
        gemm_sp<3><<<dim3(12, 16), 256, 0, stream>>>(yh, yl, wh + W_MLP1, wl + W_MLP1, mlp_b1 + l * 1536,
                                                     nullptr, nullptr, nullptr, nullptr, nullptr, mh, ml,
                                                     2048, 1536, 768);
        gemm_sp<4><<<dim3(6, 16), 256, 0, stream>>>(mh, ml, wh + W_MLP2, wl + W_MLP2, mlp_b2 + l * 768,
                                                    t, nullptr, nullptr, nullptr, t, nullptr, nullptr,
                                                    2048, 768, 1536);
    }

    // output head
    fsplit<<<1536, 256, 0, stream>>>(t, yh, yl, 393216);
    fsplit<<<96, 256, 0, stream>>>(op_w1, wh, wl, 24576);
    fsplit<<<96, 256, 0, stream>>>(op_w2, wh + 131072, wl + 131072, 24576);
    gemm_sp<5><<<dim3(1, 16), 256, 0, stream>>>(yh, yl, wh, wl, op_b1, nullptr, nullptr,
                                                nullptr, nullptr, nullptr, o1h, o1l, 2048, 128, 768);
    gemm_sp<6><<<dim3(6, 16), 256, 0, stream>>>(o1h, o1l, wh + 131072, wl + 131072, op_b2, nullptr,
                                                nullptr, nullptr, nullptr, oph2, nullptr, nullptr,
                                                2048, 768, 128);
    fold_gate<<<2048, 256, 0, stream>>>(oph2, x, ag_wg, ag_bngw, ag_bngb,
                                        ag_wx, ag_bnxw, ag_bnxb, ag_psiw, ag_psib, out);
}